// Round 14
// baseline (77.709 us; speedup 1.0000x reference)
//
#include <hip/hip_runtime.h>
#include <hip/hip_bf16.h>
#include <stdint.h>

#define T_TOK 8192
#define DIM   1024
#define NEXP  8
#define BM    128
#define BN    128
#define BK2   32

typedef __bf16 bf16_t;
typedef bf16_t bf16x8 __attribute__((ext_vector_type(8)));
typedef bf16_t bf16x4 __attribute__((ext_vector_type(4)));
typedef float  f32x4  __attribute__((ext_vector_type(4)));

// ---- workspace layout (bytes) ----
// cnt: 64 counters, EACH ON ITS OWN 64B CACHE LINE (atomic ping-pong fix, R6)
#define WS_CNT    0                  // 64 * 16 ints = 4 KB
#define CIDX(p)   ((p) << 4)
#define WS_LIST   8192               // 64 * 8192 ints = 2 MB
#define WS_XBF    (4u << 20)         // T*D bf16 = 16 MB
#define WS_WT     (20u << 20)        // WT 8*D*D bf16 = 16 MB (total 36 MB)

// async 16B global -> LDS (lds dest is wave-uniform base; HW adds lane*16)
__device__ __forceinline__ void gload16(const void* g, void* l) {
    __builtin_amdgcn_global_load_lds(
        (const __attribute__((address_space(1))) unsigned int*)g,
        (__attribute__((address_space(3))) unsigned int*)l, 16, 0, 0);
}

// BK2=32 tile: row = 64B = 4 chunks of 16B; chunk' = chunk ^ ((r>>1)&3)
// -> max 2-way bank aliasing on ds_read_b128 (free). k in elements.
__device__ __forceinline__ int swz32(int r, int k) {
    return ((r * BK2 + k) * 2) ^ (((r >> 1) & 3) << 4);
}

#define WAITCNT_VM0()   do { asm volatile("s_waitcnt vmcnt(0)" ::: "memory"); \
                             __builtin_amdgcn_sched_barrier(0); } while (0)
// steady state: 6 loads (tile k) + 6 just-issued (tile k+1); vmcnt(6) waits
// only tile-k's, prefetch stays in flight across barriers (T4)
#define WAITCNT_VM6()   do { asm volatile("s_waitcnt vmcnt(6)" ::: "memory"); \
                             __builtin_amdgcn_sched_barrier(0); } while (0)
#define BARRIER()       do { __builtin_amdgcn_s_barrier(); \
                             __builtin_amdgcn_sched_barrier(0); } while (0)

// ------------------------------------------------------------------
// zero_cnt: zero the 4 KB counter region
// ------------------------------------------------------------------
__global__ void zero_cnt(int4* cnt4) {
    cnt4[threadIdx.x] = int4{0, 0, 0, 0};   // 256 * 16 B = 4 KB
}

// ------------------------------------------------------------------
// pre1 (R13-exact): blocks [0,1024) = route (8 tokens each);
// blocks [1024,3072) = single-expert transpose WT[e][f][d]=bf16(ew[e][d][f]).
// Sequential ranges (NOT interleaved - R12 lesson).
// ------------------------------------------------------------------
__global__ __launch_bounds__(256) void pre1(const float* __restrict__ x,
                                            const float* __restrict__ gw,
                                            const float* __restrict__ gb,
                                            const float* __restrict__ ew,
                                            bf16_t* __restrict__ xbf,
                                            bf16_t* __restrict__ wt,
                                            int* __restrict__ cnt,
                                            int* __restrict__ list) {
    __shared__ __align__(16) float sh[NEXP * DIM];   // 32 KB
    int bx  = blockIdx.x;
    int tid = threadIdx.x;
    if (bx < 1024) {
        // ---------------- route: 8 tokens/block (R9-proven) ----------------
        float4 gb0 = *(const float4*)gb;
        float4 gb1 = *(const float4*)(gb + 4);
        float gbl[8] = {gb0.x, gb0.y, gb0.z, gb0.w, gb1.x, gb1.y, gb1.z, gb1.w};
        float* gwt = sh;
        const float4* gw4 = (const float4*)gw;        // gw is [D][8] fp32
        #pragma unroll
        for (int i = 0; i < 8; i++) {
            int f4 = tid + i * 256;
            float4 v = gw4[f4];
            int d  = f4 >> 1;
            int e0 = (f4 & 1) * 4;
            gwt[(e0 + 0) * DIM + d] = v.x;
            gwt[(e0 + 1) * DIM + d] = v.y;
            gwt[(e0 + 2) * DIM + d] = v.z;
            gwt[(e0 + 3) * DIM + d] = v.w;
        }
        __syncthreads();
        int wid  = tid >> 6;
        int lane = tid & 63;
        const float4* gwt4 = (const float4*)gwt;
        for (int tt = 0; tt < 2; tt++) {
            int t = bx * 8 + wid * 2 + tt;
            const float4* xr4 = (const float4*)(x + (size_t)t * DIM);
            float acc[NEXP] = {};
            #pragma unroll
            for (int j = 0; j < 4; j++) {
                int c4 = j * 64 + lane;               // float4 index in row
                float4 v = xr4[c4];
                bf16x4 b;
                b[0] = (bf16_t)v.x; b[1] = (bf16_t)v.y;
                b[2] = (bf16_t)v.z; b[3] = (bf16_t)v.w;
                *(bf16x4*)(xbf + (size_t)t * DIM + c4 * 4) = b;
                #pragma unroll
                for (int e = 0; e < NEXP; e++) {
                    float4 g = gwt4[e * 256 + c4];    // conflict-free
                    acc[e] += v.x * g.x + v.y * g.y + v.z * g.z + v.w * g.w;
                }
            }
            for (int off = 32; off >= 1; off >>= 1)
                #pragma unroll
                for (int e = 0; e < NEXP; e++)
                    acc[e] += __shfl_xor(acc[e], off, 64);
            if (lane == 0) {
                float logit[NEXP];
                #pragma unroll
                for (int e = 0; e < NEXP; e++) logit[e] = acc[e] + gbl[e];
                int b1 = 0; float best = logit[0];
                for (int e = 1; e < NEXP; e++) if (logit[e] > best) { best = logit[e]; b1 = e; }
                int b2 = -1; float best2 = -3.0e38f;
                for (int e = 0; e < NEXP; e++) {
                    if (e == b1) continue;
                    if (logit[e] > best2) { best2 = logit[e]; b2 = e; }
                }
                int a = min(b1, b2), bb = max(b1, b2);
                int p = a * 8 + bb;
                int pos = atomicAdd(&cnt[CIDX(p)], 1);   // line-padded counter
                list[p * T_TOK + pos] = t;
            }
        }
    } else {
        // ---- single-expert transpose: WT[e][f][d] = bf16(ew[e][d][f]) ----
        int bz  = bx - 1024;               // 0..2047
        int g   = bz >> 8;                 // expert e
        int rem = bz & 255;
        int f0  = (rem & 15) * 64;
        int d0  = (rem >> 4) * 64;
        float (*tile)[65] = (float (*)[65])sh;
        const float* s1 = ew + ((size_t)g * DIM + d0) * DIM + f0;
        int fl = (tid & 15) * 4;
        int dl = tid >> 4;
        #pragma unroll
        for (int i = 0; i < 4; i++) {
            int d = dl + i * 16;
            float4 u = *(const float4*)(s1 + (size_t)d * DIM + fl);
            tile[d][fl + 0] = u.x; tile[d][fl + 1] = u.y;
            tile[d][fl + 2] = u.z; tile[d][fl + 3] = u.w;
        }
        __syncthreads();
        bf16_t* dst = wt + ((size_t)g * DIM + f0) * DIM + d0;
        int dl2 = (tid & 7) * 8;
        int fl2 = tid >> 3;
        #pragma unroll
        for (int i = 0; i < 2; i++) {
            int f = fl2 + i * 32;
            bf16x8 o;
            #pragma unroll
            for (int c = 0; c < 8; c++) o[c] = (bf16_t)tile[dl2 + c][f];
            *(bf16x8*)(dst + (size_t)f * DIM + dl2) = o;
        }
    }
}

// ------------------------------------------------------------------
// moe_gemm2: dual-MFMA grouped GEMM. Per item, stage WT[e1] AND WT[e2]
// panels; acc = mfma(a,b1,acc); acc = mfma(a,b2,acc) -> x@(W1+W2) in fp32
// accum WITHOUT the pairsum pass or WSUM traffic. 128x128/item, BK=32,
// 4 waves (2x2), counted vmcnt(6) double-buffer, bijective XCD partition.
// LDS 49 KB -> 3 blocks/CU.
// ------------------------------------------------------------------
__global__ __launch_bounds__(256, 3) void moe_gemm2(const bf16_t* __restrict__ xbf,
                                                    const bf16_t* __restrict__ wt,
                                                    const int* __restrict__ cnt,
                                                    const int* __restrict__ list,
                                                    float* __restrict__ out) {
    __shared__ __align__(16) bf16_t As[2][BM * BK2];
    __shared__ __align__(16) bf16_t B1[2][BN * BK2];
    __shared__ __align__(16) bf16_t B2[2][BN * BK2];
    __shared__ int toks[BM];
    __shared__ int s_desc[128];
    __shared__ int s_ntile;
    int tid  = threadIdx.x;
    int lane = tid & 63;
    int wv   = tid >> 6;
    int wm   = wv >> 1, wn = wv & 1;

    if (tid < 64) {
        int c  = cnt[CIDX(tid)];
        int tp = (c + BM - 1) >> 7;
        int pre = 0, tot = 0;
        for (int i = 0; i < 64; i++) {
            int v = __shfl(tp, i, 64);
            if (i < tid) pre += v;
            tot += v;
        }
        for (int j = 0; j < tp; j++)
            s_desc[pre + j] = tid | ((j * BM) << 8);
        if (tid == 0) s_ntile = tot;
    }
    __syncthreads();
    int nwork = s_ntile * (DIM / BN);
    // bijective XCD-balanced mapping (runtime nwork, R9)
    int q = nwork >> 3, r = nwork & 7;
    int xcd  = blockIdx.x & 7;
    int slot = blockIdx.x >> 3;
    int share = q + (xcd < r ? 1 : 0);
    if (slot >= share) return;
    int w = xcd * q + min(xcd, r) + slot;

    int dsc = s_desc[w >> 3];
    int n0  = (w & 7) * BN;
    int p   = dsc & 63;
    int m0  = dsc >> 8;
    int e1  = p >> 3, e2 = p & 7;
    int cp  = cnt[CIDX(p)];
    int valid = min(BM, cp - m0);
    if (tid < BM) toks[tid] = list[p * T_TOK + m0 + min(tid, valid - 1)];
    __syncthreads();

    // pre-swizzled gather sources (LDS dest stays linear; swizzle on read)
    const bf16_t *asrc[2], *b1src[2], *b2src[2];
    const bf16_t* w1 = wt + (size_t)e1 * DIM * DIM;
    const bf16_t* w2 = wt + (size_t)e2 * DIM * DIM;
    #pragma unroll
    for (int i = 0; i < 2; i++) {
        int c = i * 256 + tid;
        int rr = c >> 2, js = (c & 3) ^ ((rr >> 1) & 3);
        asrc[i]  = xbf + (size_t)toks[rr] * DIM + js * 8;
        b1src[i] = w1 + (size_t)(n0 + rr) * DIM + js * 8;
        b2src[i] = w2 + (size_t)(n0 + rr) * DIM + js * 8;
    }

    f32x4 acc[4][4] = {};
    int lr = lane & 15;
    int lk = (lane >> 4) * 8;

    // ---- prologue: stage K-tile 0 (6 loads/thread-of-wave) ----
    #pragma unroll
    for (int i = 0; i < 2; i++) {
        int lds = (i * 256 + wv * 64) * 8;
        gload16(asrc[i],  &As[0][lds]);
        gload16(b1src[i], &B1[0][lds]);
        gload16(b2src[i], &B2[0][lds]);
    }

    for (int ks = 0; ks < DIM / BK2; ks++) {
        int cur = ks & 1;
        if (ks < DIM / BK2 - 1) {
            int k1 = (ks + 1) * BK2;
            #pragma unroll
            for (int i = 0; i < 2; i++) {
                int lds = (i * 256 + wv * 64) * 8;
                gload16(asrc[i] + k1,  &As[cur ^ 1][lds]);
                gload16(b1src[i] + k1, &B1[cur ^ 1][lds]);
                gload16(b2src[i] + k1, &B2[cur ^ 1][lds]);
            }
            WAITCNT_VM6();      // wait only tile-ks loads; prefetch in flight
        } else {
            WAITCNT_VM0();      // last tile: drain
        }
        BARRIER();
        const char* Ab  = (const char*)As[cur];
        const char* B1b = (const char*)B1[cur];
        const char* B2b = (const char*)B2[cur];
        bf16x8 af[4], b1f[4], b2f[4];
        #pragma unroll
        for (int mf = 0; mf < 4; mf++)
            af[mf] = *(const bf16x8*)(Ab + swz32(wm * 64 + mf * 16 + lr, lk));
        #pragma unroll
        for (int nf = 0; nf < 4; nf++) {
            b1f[nf] = *(const bf16x8*)(B1b + swz32(wn * 64 + nf * 16 + lr, lk));
            b2f[nf] = *(const bf16x8*)(B2b + swz32(wn * 64 + nf * 16 + lr, lk));
        }
        // 16 independent MFMAs per group; groups chain through acc (latency
        // covered by the 16-wide independence)
        #pragma unroll
        for (int mf = 0; mf < 4; mf++)
            #pragma unroll
            for (int nf = 0; nf < 4; nf++)
                acc[mf][nf] = __builtin_amdgcn_mfma_f32_16x16x32_bf16(
                    af[mf], b1f[nf], acc[mf][nf], 0, 0, 0);
        #pragma unroll
        for (int mf = 0; mf < 4; mf++)
            #pragma unroll
            for (int nf = 0; nf < 4; nf++)
                acc[mf][nf] = __builtin_amdgcn_mfma_f32_16x16x32_bf16(
                    af[mf], b2f[nf], acc[mf][nf], 0, 0, 0);
        BARRIER();              // buf cur free for prefetch at step ks+1
    }

    // ---- C write: per 16x16 frag row=(lane>>4)*4+reg, col=lane&15 ----
    #pragma unroll
    for (int mf = 0; mf < 4; mf++) {
        #pragma unroll
        for (int reg = 0; reg < 4; reg++) {
            int rl = wm * 64 + mf * 16 + (lane >> 4) * 4 + reg;
            if (rl < valid) {
                size_t trow = (size_t)toks[rl] * DIM;
                #pragma unroll
                for (int nf = 0; nf < 4; nf++)
                    out[trow + n0 + wn * 64 + nf * 16 + lr] = acc[mf][nf][reg];
            }
        }
    }
}

// ------------------------------------------------------------------
extern "C" void kernel_launch(void* const* d_in, const int* in_sizes, int n_in,
                              void* d_out, int out_size, void* d_ws, size_t ws_size,
                              hipStream_t stream) {
    const float* x  = (const float*)d_in[0];
    const float* gw = (const float*)d_in[1];
    const float* gb = (const float*)d_in[2];
    const float* ew = (const float*)d_in[3];
    float* out = (float*)d_out;
    char* ws = (char*)d_ws;
    int*    cnt  = (int*)(ws + WS_CNT);
    int*    list = (int*)(ws + WS_LIST);
    bf16_t* xbf  = (bf16_t*)(ws + WS_XBF);
    bf16_t* wt   = (bf16_t*)(ws + WS_WT);

    zero_cnt<<<dim3(1), 256, 0, stream>>>((int4*)cnt);
    pre1<<<dim3(3072), 256, 0, stream>>>(x, gw, gb, ew, xbf, wt, cnt, list);
    moe_gemm2<<<dim3(1024), 256, 0, stream>>>(xbf, wt, cnt, list, out);
}

// Round 15
// 71.784 us; speedup vs baseline: 1.0825x; 1.0825x over previous
//
#include <hip/hip_runtime.h>
#include <hip/hip_bf16.h>
#include <stdint.h>

#define T_TOK 8192
#define DIM   1024
#define NEXP  8
#define BM    128
#define BN    128
#define BK2   32

typedef __bf16 bf16_t;
typedef bf16_t bf16x8 __attribute__((ext_vector_type(8)));
typedef bf16_t bf16x4 __attribute__((ext_vector_type(4)));
typedef float  f32x4  __attribute__((ext_vector_type(4)));

// ---- workspace layout (bytes) ----
// cnt: 64 counters, EACH ON ITS OWN 64B CACHE LINE (atomic ping-pong fix, R6)
#define WS_CNT    0                  // 64 * 16 ints = 4 KB
#define CIDX(p)   ((p) << 4)
#define WS_LIST   8192               // 64 * 8192 ints = 2 MB
#define WS_XBF    (4u << 20)         // T*D bf16 = 16 MB
#define WS_WT     (20u << 20)        // WT 8*D*D bf16 = 16 MB (total 36 MB; no WSUM)

// pair index tables: pk -> (a,b), a<b
__device__ const int d_PA[28] = {0,0,0,0,0,0,0,1,1,1,1,1,1,2,2,2,2,2,3,3,3,3,4,4,4,5,5,6};
__device__ const int d_PB[28] = {1,2,3,4,5,6,7,2,3,4,5,6,7,3,4,5,6,7,4,5,6,7,5,6,7,6,7,7};

// async 16B global -> LDS (lds dest is wave-uniform base; HW adds lane*16)
__device__ __forceinline__ void gload16(const void* g, void* l) {
    __builtin_amdgcn_global_load_lds(
        (const __attribute__((address_space(1))) unsigned int*)g,
        (__attribute__((address_space(3))) unsigned int*)l, 16, 0, 0);
}

// BK2=32 tile: row = 64B = 4 chunks of 16B; chunk' = chunk ^ ((r>>1)&3)
// -> max 2-way bank aliasing on ds_read_b128 (free). k in elements.
__device__ __forceinline__ int swz32(int r, int k) {
    return ((r * BK2 + k) * 2) ^ (((r >> 1) & 3) << 4);
}

#define WAITCNT_VM0()   do { asm volatile("s_waitcnt vmcnt(0)" ::: "memory"); \
                             __builtin_amdgcn_sched_barrier(0); } while (0)
// steady state: A(k) 2 gloads + B(k+1) 4 reg-loads + A(k+1) 2 gloads = 8
// outstanding; vmcnt(6) retires the 2 oldest = A(k). Prefetch stays in flight.
#define WAITCNT_VM6()   do { asm volatile("s_waitcnt vmcnt(6)" ::: "memory"); \
                             __builtin_amdgcn_sched_barrier(0); } while (0)
#define WAITCNT_LGKM0() do { asm volatile("s_waitcnt lgkmcnt(0)" ::: "memory"); \
                             __builtin_amdgcn_sched_barrier(0); } while (0)
#define BARRIER()       do { __builtin_amdgcn_s_barrier(); \
                             __builtin_amdgcn_sched_barrier(0); } while (0)

// ------------------------------------------------------------------
// zero_cnt: zero the 4 KB counter region
// ------------------------------------------------------------------
__global__ void zero_cnt(int4* cnt4) {
    cnt4[threadIdx.x] = int4{0, 0, 0, 0};   // 256 * 16 B = 4 KB
}

// ------------------------------------------------------------------
// pre1 (R13-exact): blocks [0,1024) = route (8 tokens each);
// blocks [1024,3072) = single-expert transpose WT[e][f][d]=bf16(ew[e][d][f]).
// Sequential ranges (NOT interleaved - R12 lesson).
// ------------------------------------------------------------------
__global__ __launch_bounds__(256) void pre1(const float* __restrict__ x,
                                            const float* __restrict__ gw,
                                            const float* __restrict__ gb,
                                            const float* __restrict__ ew,
                                            bf16_t* __restrict__ xbf,
                                            bf16_t* __restrict__ wt,
                                            int* __restrict__ cnt,
                                            int* __restrict__ list) {
    __shared__ __align__(16) float sh[NEXP * DIM];   // 32 KB
    int bx  = blockIdx.x;
    int tid = threadIdx.x;
    if (bx < 1024) {
        // ---------------- route: 8 tokens/block (R9-proven) ----------------
        float4 gb0 = *(const float4*)gb;
        float4 gb1 = *(const float4*)(gb + 4);
        float gbl[8] = {gb0.x, gb0.y, gb0.z, gb0.w, gb1.x, gb1.y, gb1.z, gb1.w};
        float* gwt = sh;
        const float4* gw4 = (const float4*)gw;        // gw is [D][8] fp32
        #pragma unroll
        for (int i = 0; i < 8; i++) {
            int f4 = tid + i * 256;
            float4 v = gw4[f4];
            int d  = f4 >> 1;
            int e0 = (f4 & 1) * 4;
            gwt[(e0 + 0) * DIM + d] = v.x;
            gwt[(e0 + 1) * DIM + d] = v.y;
            gwt[(e0 + 2) * DIM + d] = v.z;
            gwt[(e0 + 3) * DIM + d] = v.w;
        }
        __syncthreads();
        int wid  = tid >> 6;
        int lane = tid & 63;
        const float4* gwt4 = (const float4*)gwt;
        for (int tt = 0; tt < 2; tt++) {
            int t = bx * 8 + wid * 2 + tt;
            const float4* xr4 = (const float4*)(x + (size_t)t * DIM);
            float acc[NEXP] = {};
            #pragma unroll
            for (int j = 0; j < 4; j++) {
                int c4 = j * 64 + lane;               // float4 index in row
                float4 v = xr4[c4];
                bf16x4 b;
                b[0] = (bf16_t)v.x; b[1] = (bf16_t)v.y;
                b[2] = (bf16_t)v.z; b[3] = (bf16_t)v.w;
                *(bf16x4*)(xbf + (size_t)t * DIM + c4 * 4) = b;
                #pragma unroll
                for (int e = 0; e < NEXP; e++) {
                    float4 g = gwt4[e * 256 + c4];    // conflict-free
                    acc[e] += v.x * g.x + v.y * g.y + v.z * g.z + v.w * g.w;
                }
            }
            for (int off = 32; off >= 1; off >>= 1)
                #pragma unroll
                for (int e = 0; e < NEXP; e++)
                    acc[e] += __shfl_xor(acc[e], off, 64);
            if (lane == 0) {
                float logit[NEXP];
                #pragma unroll
                for (int e = 0; e < NEXP; e++) logit[e] = acc[e] + gbl[e];
                int b1 = 0; float best = logit[0];
                for (int e = 1; e < NEXP; e++) if (logit[e] > best) { best = logit[e]; b1 = e; }
                int b2 = -1; float best2 = -3.0e38f;
                for (int e = 0; e < NEXP; e++) {
                    if (e == b1) continue;
                    if (logit[e] > best2) { best2 = logit[e]; b2 = e; }
                }
                int a = min(b1, b2), bb = max(b1, b2);
                int p = a * 8 + bb;
                int pos = atomicAdd(&cnt[CIDX(p)], 1);   // line-padded counter
                list[p * T_TOK + pos] = t;
            }
        }
    } else {
        // ---- single-expert transpose: WT[e][f][d] = bf16(ew[e][d][f]) ----
        int bz  = bx - 1024;               // 0..2047
        int g   = bz >> 8;                 // expert e
        int rem = bz & 255;
        int f0  = (rem & 15) * 64;
        int d0  = (rem >> 4) * 64;
        float (*tile)[65] = (float (*)[65])sh;
        const float* s1 = ew + ((size_t)g * DIM + d0) * DIM + f0;
        int fl = (tid & 15) * 4;
        int dl = tid >> 4;
        #pragma unroll
        for (int i = 0; i < 4; i++) {
            int d = dl + i * 16;
            float4 u = *(const float4*)(s1 + (size_t)d * DIM + fl);
            tile[d][fl + 0] = u.x; tile[d][fl + 1] = u.y;
            tile[d][fl + 2] = u.z; tile[d][fl + 3] = u.w;
        }
        __syncthreads();
        bf16_t* dst = wt + ((size_t)g * DIM + f0) * DIM + d0;
        int dl2 = (tid & 7) * 8;
        int fl2 = tid >> 3;
        #pragma unroll
        for (int i = 0; i < 2; i++) {
            int f = fl2 + i * 32;
            bf16x8 o;
            #pragma unroll
            for (int c = 0; c < 8; c++) o[c] = (bf16_t)tile[dl2 + c][f];
            *(bf16x8*)(dst + (size_t)f * DIM + dl2) = o;
        }
    }
}

// ------------------------------------------------------------------
// moe_gemm3: grouped GEMM with pair-sum fused into B-STAGING (not MFMA).
// Per K-step: B(k)=WT[e1]+WT[e2] summed in regs (loaded step k-1),
// ds_write'd swizzled; A via gload16 (linear dest, pre-swizzled src).
// MFMA count and LDS (32KB, 4 blocks/CU) identical to R11; WSUM round-trip
// and pairsum dispatch eliminated. Counted vmcnt(6), bijective XCD map.
// ------------------------------------------------------------------
__global__ __launch_bounds__(256, 4) void moe_gemm3(const bf16_t* __restrict__ xbf,
                                                    const bf16_t* __restrict__ wt,
                                                    const int* __restrict__ cnt,
                                                    const int* __restrict__ list,
                                                    float* __restrict__ out) {
    __shared__ __align__(16) bf16_t As[2][BM * BK2];   // 2 x 8 KB
    __shared__ __align__(16) bf16_t Bs[2][BN * BK2];   // 2 x 8 KB
    __shared__ int toks[BM];
    __shared__ int s_desc[128];
    __shared__ int s_ntile;
    int tid  = threadIdx.x;
    int lane = tid & 63;
    int wv   = tid >> 6;
    int wm   = wv >> 1, wn = wv & 1;

    if (tid < 64) {
        int c  = cnt[CIDX(tid)];
        int tp = (c + BM - 1) >> 7;
        int pre = 0, tot = 0;
        for (int i = 0; i < 64; i++) {
            int v = __shfl(tp, i, 64);
            if (i < tid) pre += v;
            tot += v;
        }
        for (int j = 0; j < tp; j++)
            s_desc[pre + j] = tid | ((j * BM) << 8);
        if (tid == 0) s_ntile = tot;
    }
    __syncthreads();
    int nwork = s_ntile * (DIM / BN);
    // bijective XCD-balanced mapping (runtime nwork, R9)
    int q = nwork >> 3, r = nwork & 7;
    int xcd  = blockIdx.x & 7;
    int slot = blockIdx.x >> 3;
    int share = q + (xcd < r ? 1 : 0);
    if (slot >= share) return;
    int w = xcd * q + min(xcd, r) + slot;

    int dsc = s_desc[w >> 3];
    int n0  = (w & 7) * BN;
    int p   = dsc & 63;
    int m0  = dsc >> 8;
    int e1  = p >> 3, e2 = p & 7;
    int cp  = cnt[CIDX(p)];
    int valid = min(BM, cp - m0);
    if (tid < BM) toks[tid] = list[p * T_TOK + m0 + min(tid, valid - 1)];
    __syncthreads();

    // A sources: pre-swizzled gather (gload16, LDS dest linear)
    const bf16_t* asrc[2];
    #pragma unroll
    for (int i = 0; i < 2; i++) {
        int c = i * 256 + tid;
        int rr = c >> 2, js = (c & 3) ^ ((rr >> 1) & 3);
        asrc[i] = xbf + (size_t)toks[rr] * DIM + js * 8;
    }
    // B sources: reg-staged, NO source swizzle (ds_write goes to swizzled addr)
    const bf16_t* w1 = wt + (size_t)e1 * DIM * DIM;
    const bf16_t* w2 = wt + (size_t)e2 * DIM * DIM;
    const bf16_t* b1p[2];
    const bf16_t* b2p[2];
    int bofs[2];
    #pragma unroll
    for (int i = 0; i < 2; i++) {
        int c = i * 256 + tid;
        int f = c >> 2, j = c & 3;
        b1p[i] = w1 + (size_t)(n0 + f) * DIM + j * 8;
        b2p[i] = w2 + (size_t)(n0 + f) * DIM + j * 8;
        bofs[i] = swz32(f, j * 8);
    }

    f32x4 acc[4][4] = {};
    int lr = lane & 15;
    int lk = (lane >> 4) * 8;

    // ---- prologue: B(0) -> regs (issued FIRST), A(0) -> gload16 ----
    bf16x8 br1[2], br2[2];
    #pragma unroll
    for (int i = 0; i < 2; i++) { br1[i] = *(const bf16x8*)b1p[i];
                                  br2[i] = *(const bf16x8*)b2p[i]; }
    #pragma unroll
    for (int i = 0; i < 2; i++)
        gload16(asrc[i], &As[0][(i * 256 + wv * 64) * 8]);

    for (int ks = 0; ks < DIM / BK2; ks++) {
        int cur = ks & 1;
        // ---- ds_write B(ks) = br1+br2 (compiler's counted wait covers regs,
        //      leaving A(ks) gloads in flight: B issued before A) ----
        #pragma unroll
        for (int i = 0; i < 2; i++) {
            bf16x8 o;
            #pragma unroll
            for (int qq = 0; qq < 8; qq++)
                o[qq] = (bf16_t)((float)br1[i][qq] + (float)br2[i][qq]);
            *(bf16x8*)((char*)Bs[cur] + bofs[i]) = o;
        }
        if (ks < DIM / BK2 - 1) {
            int k1 = (ks + 1) * BK2;
            // B(ks+1) reg loads first, then A(ks+1) gloads (order = vmcnt count)
            #pragma unroll
            for (int i = 0; i < 2; i++) { br1[i] = *(const bf16x8*)(b1p[i] + k1);
                                          br2[i] = *(const bf16x8*)(b2p[i] + k1); }
            #pragma unroll
            for (int i = 0; i < 2; i++)
                gload16(asrc[i] + k1, &As[cur ^ 1][(i * 256 + wv * 64) * 8]);
            WAITCNT_LGKM0();    // my ds_writes visible
            WAITCNT_VM6();      // retire A(ks); B(ks+1)+A(ks+1) stay in flight
        } else {
            WAITCNT_LGKM0();
            WAITCNT_VM0();      // last tile: drain
        }
        BARRIER();
        const char* Ab = (const char*)As[cur];
        const char* Bb = (const char*)Bs[cur];
        bf16x8 af[4], bfr[4];
        #pragma unroll
        for (int mf = 0; mf < 4; mf++)
            af[mf] = *(const bf16x8*)(Ab + swz32(wm * 64 + mf * 16 + lr, lk));
        #pragma unroll
        for (int nf = 0; nf < 4; nf++)
            bfr[nf] = *(const bf16x8*)(Bb + swz32(wn * 64 + nf * 16 + lr, lk));
        #pragma unroll
        for (int mf = 0; mf < 4; mf++)
            #pragma unroll
            for (int nf = 0; nf < 4; nf++)
                acc[mf][nf] = __builtin_amdgcn_mfma_f32_16x16x32_bf16(
                    af[mf], bfr[nf], acc[mf][nf], 0, 0, 0);
        BARRIER();              // Bs[cur]/As[cur] free for step ks+1 writes
    }

    // ---- C write: per 16x16 frag row=(lane>>4)*4+reg, col=lane&15 ----
    #pragma unroll
    for (int mf = 0; mf < 4; mf++) {
        #pragma unroll
        for (int reg = 0; reg < 4; reg++) {
            int rl = wm * 64 + mf * 16 + (lane >> 4) * 4 + reg;
            if (rl < valid) {
                size_t trow = (size_t)toks[rl] * DIM;
                #pragma unroll
                for (int nf = 0; nf < 4; nf++)
                    out[trow + n0 + wn * 64 + nf * 16 + lr] = acc[mf][nf][reg];
            }
        }
    }
}

// ------------------------------------------------------------------
extern "C" void kernel_launch(void* const* d_in, const int* in_sizes, int n_in,
                              void* d_out, int out_size, void* d_ws, size_t ws_size,
                              hipStream_t stream) {
    const float* x  = (const float*)d_in[0];
    const float* gw = (const float*)d_in[1];
    const float* gb = (const float*)d_in[2];
    const float* ew = (const float*)d_in[3];
    float* out = (float*)d_out;
    char* ws = (char*)d_ws;
    int*    cnt  = (int*)(ws + WS_CNT);
    int*    list = (int*)(ws + WS_LIST);
    bf16_t* xbf  = (bf16_t*)(ws + WS_XBF);
    bf16_t* wt   = (bf16_t*)(ws + WS_WT);

    zero_cnt<<<dim3(1), 256, 0, stream>>>((int4*)cnt);
    pre1<<<dim3(3072), 256, 0, stream>>>(x, gw, gb, ew, xbf, wt, cnt, list);
    moe_gemm3<<<dim3(1024), 256, 0, stream>>>(xbf, wt, cnt, list, out);
}

// Round 16
// 68.893 us; speedup vs baseline: 1.1280x; 1.0420x over previous
//
#include <hip/hip_runtime.h>
#include <hip/hip_bf16.h>
#include <stdint.h>

#define T_TOK 8192
#define DIM   1024
#define NEXP  8
#define BM    128
#define BN    128
#define BK2   32
#define NR_ROUTE 1024    // route blocks, 8 tokens each (R9 config)

typedef __bf16 bf16_t;
typedef bf16_t bf16x8 __attribute__((ext_vector_type(8)));
typedef bf16_t bf16x4 __attribute__((ext_vector_type(4)));
typedef float  f32x4  __attribute__((ext_vector_type(4)));

// ---- workspace layout (bytes) ----
// cnt: 64 counters, EACH ON ITS OWN 64B CACHE LINE (atomic ping-pong fix, R6)
#define WS_CNT    0                  // 64 * 16 ints = 4 KB
#define CIDX(p)   ((p) << 4)
#define WS_LIST   8192               // 64 * 8192 ints = 2 MB
#define WS_XBF    (4u << 20)         // T*D bf16 = 16 MB
#define WS_W2     (20u << 20)        // WSUM 28*2MB = 56 MB (psum) or WT 16MB (fallback)
#define WS_NEED_PSUM ((size_t)76 << 20)

// pair index tables: pk -> (a,b), a<b
__device__ const int d_PA[28] = {0,0,0,0,0,0,0,1,1,1,1,1,1,2,2,2,2,2,3,3,3,3,4,4,4,5,5,6};
__device__ const int d_PB[28] = {1,2,3,4,5,6,7,2,3,4,5,6,7,3,4,5,6,7,4,5,6,7,5,6,7,6,7,7};

// async 16B global -> LDS (lds dest is wave-uniform base; HW adds lane*16)
__device__ __forceinline__ void gload16(const void* g, void* l) {
    __builtin_amdgcn_global_load_lds(
        (const __attribute__((address_space(1))) unsigned int*)g,
        (__attribute__((address_space(3))) unsigned int*)l, 16, 0, 0);
}

// BK2=32 tile: row = 64B = 4 chunks of 16B; chunk' = chunk ^ ((r>>1)&3)
// -> max 2-way bank aliasing on ds_read_b128 (free). k in elements.
__device__ __forceinline__ int swz32(int r, int k) {
    return ((r * BK2 + k) * 2) ^ (((r >> 1) & 3) << 4);
}

#define WAITCNT_VM0()   do { asm volatile("s_waitcnt vmcnt(0)" ::: "memory"); \
                             __builtin_amdgcn_sched_barrier(0); } while (0)
#define WAITCNT_VM4()   do { asm volatile("s_waitcnt vmcnt(4)" ::: "memory"); \
                             __builtin_amdgcn_sched_barrier(0); } while (0)
#define WAITCNT_LGKM0() do { asm volatile("s_waitcnt lgkmcnt(0)" ::: "memory"); \
                             __builtin_amdgcn_sched_barrier(0); } while (0)
#define BARRIER()       do { __builtin_amdgcn_s_barrier(); \
                             __builtin_amdgcn_sched_barrier(0); } while (0)

// ------------------------------------------------------------------
// zero_cnt: zero the 4 KB counter region (replaces hipMemsetAsync)
// ------------------------------------------------------------------
__global__ void zero_cnt(int4* cnt4) {
    cnt4[threadIdx.x] = int4{0, 0, 0, 0};   // 256 * 16 B = 4 KB
}

// ------------------------------------------------------------------
// fused_pre (R11-exact):
//   blocks [0,1024): route, 8 tokens each (R9-proven config)
//   PSUM=1: blocks [1024,1536): pairsum-v3 — block owns (f0:64,d0:32);
//           phase 1: per expert, coalesced fp32 rows -> LDS [32][65]
//           -> transpose-convert -> bf16 T[e][64][36] (ew read ONCE);
//           phase 2: 28 pair sums streamed from LDS, 16B stores.
//   PSUM=0: blocks [1024,3072): per-expert 64x64 transpose (fallback).
// ------------------------------------------------------------------
template <int PSUM>
__global__ __launch_bounds__(256) void fused_pre(const float* __restrict__ x,
                                                 const float* __restrict__ gw,
                                                 const float* __restrict__ gb,
                                                 const float* __restrict__ ew,
                                                 bf16_t* __restrict__ xbf,
                                                 bf16_t* __restrict__ w2,
                                                 int* __restrict__ cnt,
                                                 int* __restrict__ list) {
    __shared__ __align__(16) char sh[45184];   // route 32KB | pairsum 8.3+36.9KB
    int bx  = blockIdx.x;
    int tid = threadIdx.x;
    if (bx < NR_ROUTE) {
        // ---------------- route: 8 tokens/block (R9) ----------------
        float4 gb0 = *(const float4*)gb;
        float4 gb1 = *(const float4*)(gb + 4);
        float gbl[8] = {gb0.x, gb0.y, gb0.z, gb0.w, gb1.x, gb1.y, gb1.z, gb1.w};
        float* gwt = (float*)sh;
        const float4* gw4 = (const float4*)gw;        // gw is [D][8] fp32
        #pragma unroll
        for (int i = 0; i < 8; i++) {
            int f4 = tid + i * 256;
            float4 v = gw4[f4];
            int d  = f4 >> 1;
            int e0 = (f4 & 1) * 4;
            gwt[(e0 + 0) * DIM + d] = v.x;
            gwt[(e0 + 1) * DIM + d] = v.y;
            gwt[(e0 + 2) * DIM + d] = v.z;
            gwt[(e0 + 3) * DIM + d] = v.w;
        }
        __syncthreads();
        int wid  = tid >> 6;
        int lane = tid & 63;
        const float4* gwt4 = (const float4*)gwt;
        for (int tt = 0; tt < 2; tt++) {
            int t = bx * 8 + wid * 2 + tt;
            const float4* xr4 = (const float4*)(x + (size_t)t * DIM);
            float acc[NEXP] = {};
            #pragma unroll
            for (int j = 0; j < 4; j++) {
                int c4 = j * 64 + lane;               // float4 index in row
                float4 v = xr4[c4];
                bf16x4 b;
                b[0] = (bf16_t)v.x; b[1] = (bf16_t)v.y;
                b[2] = (bf16_t)v.z; b[3] = (bf16_t)v.w;
                *(bf16x4*)(xbf + (size_t)t * DIM + c4 * 4) = b;
                #pragma unroll
                for (int e = 0; e < NEXP; e++) {
                    float4 g = gwt4[e * 256 + c4];    // conflict-free
                    acc[e] += v.x * g.x + v.y * g.y + v.z * g.z + v.w * g.w;
                }
            }
            for (int off = 32; off >= 1; off >>= 1)
                #pragma unroll
                for (int e = 0; e < NEXP; e++)
                    acc[e] += __shfl_xor(acc[e], off, 64);
            if (lane == 0) {
                float logit[NEXP];
                #pragma unroll
                for (int e = 0; e < NEXP; e++) logit[e] = acc[e] + gbl[e];
                int b1 = 0; float best = logit[0];
                for (int e = 1; e < NEXP; e++) if (logit[e] > best) { best = logit[e]; b1 = e; }
                int b2 = -1; float best2 = -3.0e38f;
                for (int e = 0; e < NEXP; e++) {
                    if (e == b1) continue;
                    if (logit[e] > best2) { best2 = logit[e]; b2 = e; }
                }
                int a = min(b1, b2), bb = max(b1, b2);
                int p = a * 8 + bb;
                int pos = atomicAdd(&cnt[CIDX(p)], 1);   // line-padded counter
                list[p * T_TOK + pos] = t;
            }
        }
    } else if (PSUM) {
        // ---- pairsum-v3: (f0:64, d0:32) tile; ew read ONCE ----
        int bz = bx - NR_ROUTE;            // 0..511
        int f0 = (bz & 15) * 64;
        int d0 = (bz >> 4) * 32;
        float (*stg)[65] = (float (*)[65])sh;          // 32 x 65 fp32 = 8320 B
        bf16_t* T = (bf16_t*)(sh + 8320);              // [8][64][36] bf16
        int fc = tid & 15, dr = tid >> 4;              // load roles
        int fr = tid >> 2, dc = tid & 3;               // transpose/pair roles
        for (int e = 0; e < 8; e++) {
            #pragma unroll
            for (int it = 0; it < 2; it++) {
                int d = dr + it * 16;
                float4 v = *(const float4*)(ew + ((size_t)e * DIM + d0 + d) * DIM
                                            + f0 + fc * 4);
                stg[d][fc * 4 + 0] = v.x; stg[d][fc * 4 + 1] = v.y;
                stg[d][fc * 4 + 2] = v.z; stg[d][fc * 4 + 3] = v.w;
            }
            __syncthreads();
            bf16x4 o0, o1;
            #pragma unroll
            for (int c = 0; c < 4; c++) o0[c] = (bf16_t)stg[dc * 8 + c][fr];
            #pragma unroll
            for (int c = 0; c < 4; c++) o1[c] = (bf16_t)stg[dc * 8 + 4 + c][fr];
            *(bf16x4*)&T[(e * 64 + fr) * 36 + dc * 8]     = o0;
            *(bf16x4*)&T[(e * 64 + fr) * 36 + dc * 8 + 4] = o1;
            __syncthreads();                           // stg reused next expert
        }
        #pragma unroll
        for (int pk = 0; pk < 28; pk++) {
            const bf16_t* ta = &T[(d_PA[pk] * 64 + fr) * 36 + dc * 8];
            const bf16_t* tb = &T[(d_PB[pk] * 64 + fr) * 36 + dc * 8];
            bf16x4 a0 = *(const bf16x4*)ta, a1 = *(const bf16x4*)(ta + 4);
            bf16x4 b0 = *(const bf16x4*)tb, b1 = *(const bf16x4*)(tb + 4);
            bf16x8 o;
            #pragma unroll
            for (int i = 0; i < 4; i++) {
                o[i]     = (bf16_t)((float)a0[i] + (float)b0[i]);
                o[4 + i] = (bf16_t)((float)a1[i] + (float)b1[i]);
            }
            *(bf16x8*)(w2 + (size_t)pk * DIM * DIM + (size_t)(f0 + fr) * DIM
                       + d0 + dc * 8) = o;
        }
    } else {
        // ---- fallback: per-expert 64x64 transpose from ew ----
        int bz  = bx - NR_ROUTE;
        int g   = bz >> 8;                 // expert e
        int rem = bz & 255;
        int f0  = (rem & 15) * 64;
        int d0  = (rem >> 4) * 64;
        float (*tile)[65] = (float (*)[65])sh;
        const float* s1 = ew + ((size_t)g * DIM + d0) * DIM + f0;
        int fl = (tid & 15) * 4;
        int dl = tid >> 4;
        #pragma unroll
        for (int i = 0; i < 4; i++) {
            int d = dl + i * 16;
            float4 u = *(const float4*)(s1 + (size_t)d * DIM + fl);
            tile[d][fl + 0] = u.x; tile[d][fl + 1] = u.y;
            tile[d][fl + 2] = u.z; tile[d][fl + 3] = u.w;
        }
        __syncthreads();
        bf16_t* dst = w2 + ((size_t)g * DIM + f0) * DIM + d0;
        int dl2 = (tid & 7) * 8;
        int fl2 = tid >> 3;
        #pragma unroll
        for (int i = 0; i < 2; i++) {
            int f = fl2 + i * 32;
            bf16x8 o;
            #pragma unroll
            for (int c = 0; c < 8; c++) o[c] = (bf16_t)tile[dl2 + c][f];
            *(bf16x8*)(dst + (size_t)f * DIM + dl2) = o;
        }
    }
}

// ------------------------------------------------------------------
// grouped GEMM (R9/R11-exact): 128x128/item, BK=32, 4 waves,
// double-buffered counted-vmcnt pipeline, bijective XCD partition.
// ------------------------------------------------------------------
template <int PSUM>
__global__ __launch_bounds__(256, 4) void moe_gemm(const bf16_t* __restrict__ xbf,
                                                   const bf16_t* __restrict__ wsrc,
                                                   const int* __restrict__ cnt,
                                                   const int* __restrict__ list,
                                                   float* __restrict__ out) {
    __shared__ __align__(16) bf16_t As[2][BM * BK2];
    __shared__ __align__(16) bf16_t Bs[2][BN * BK2];
    __shared__ int toks[BM];
    __shared__ int s_desc[128];
    __shared__ int s_ntile;
    int tid  = threadIdx.x;
    int lane = tid & 63;
    int wv   = tid >> 6;
    int wm   = wv >> 1, wn = wv & 1;

    if (tid < 64) {
        int c  = cnt[CIDX(tid)];
        int tp = (c + BM - 1) >> 7;
        int pre = 0, tot = 0;
        for (int i = 0; i < 64; i++) {
            int v = __shfl(tp, i, 64);
            if (i < tid) pre += v;
            tot += v;
        }
        for (int j = 0; j < tp; j++)
            s_desc[pre + j] = tid | ((j * BM) << 8);
        if (tid == 0) s_ntile = tot;
    }
    __syncthreads();
    int nwork = s_ntile * (DIM / BN);
    // bijective XCD-balanced mapping (runtime nwork)
    int q = nwork >> 3, r = nwork & 7;
    int xcd  = blockIdx.x & 7;
    int slot = blockIdx.x >> 3;
    int share = q + (xcd < r ? 1 : 0);
    if (slot >= share) return;
    int w = xcd * q + min(xcd, r) + slot;

    int dsc = s_desc[w >> 3];
    int n0  = (w & 7) * BN;
    int p   = dsc & 63;
    int m0  = dsc >> 8;
    int e1  = p >> 3, e2 = p & 7;
    int cp  = cnt[CIDX(p)];
    int valid = min(BM, cp - m0);
    if (tid < BM) toks[tid] = list[p * T_TOK + m0 + min(tid, valid - 1)];
    __syncthreads();

    const bf16_t* asrc[2];
    #pragma unroll
    for (int i = 0; i < 2; i++) {
        int c = i * 256 + tid;
        int rr = c >> 2, js = (c & 3) ^ ((rr >> 1) & 3);
        asrc[i] = xbf + (size_t)toks[rr] * DIM + js * 8;
    }

    f32x4 acc[4][4] = {};
    int lr = lane & 15;
    int lk = (lane >> 4) * 8;

    if (PSUM) {
        const bf16_t* bsrc[2];
        int pk = e1 * 7 - (e1 * (e1 - 1)) / 2 + (e2 - e1 - 1);
        const bf16_t* bb = wsrc + (size_t)pk * DIM * DIM;
        #pragma unroll
        for (int i = 0; i < 2; i++) {
            int c = i * 256 + tid;
            int rr = c >> 2, js = (c & 3) ^ ((rr >> 1) & 3);
            bsrc[i] = bb + (size_t)(n0 + rr) * DIM + js * 8;
        }
        #pragma unroll
        for (int i = 0; i < 2; i++)
            gload16(asrc[i], &As[0][(i * 256 + wv * 64) * 8]);
        #pragma unroll
        for (int i = 0; i < 2; i++)
            gload16(bsrc[i], &Bs[0][(i * 256 + wv * 64) * 8]);

        for (int ks = 0; ks < DIM / BK2; ks++) {
            int cur = ks & 1;
            if (ks < DIM / BK2 - 1) {
                int k1 = (ks + 1) * BK2;
                #pragma unroll
                for (int i = 0; i < 2; i++)
                    gload16(asrc[i] + k1, &As[cur ^ 1][(i * 256 + wv * 64) * 8]);
                #pragma unroll
                for (int i = 0; i < 2; i++)
                    gload16(bsrc[i] + k1, &Bs[cur ^ 1][(i * 256 + wv * 64) * 8]);
                WAITCNT_VM4();      // wait only tile-ks loads
            } else {
                WAITCNT_VM0();      // last tile: drain
            }
            BARRIER();
            const char* Ab = (const char*)As[cur];
            const char* Bb = (const char*)Bs[cur];
            bf16x8 af[4], bfr[4];
            #pragma unroll
            for (int mf = 0; mf < 4; mf++)
                af[mf] = *(const bf16x8*)(Ab + swz32(wm * 64 + mf * 16 + lr, lk));
            #pragma unroll
            for (int nf = 0; nf < 4; nf++)
                bfr[nf] = *(const bf16x8*)(Bb + swz32(wn * 64 + nf * 16 + lr, lk));
            #pragma unroll
            for (int mf = 0; mf < 4; mf++)
                #pragma unroll
                for (int nf = 0; nf < 4; nf++)
                    acc[mf][nf] = __builtin_amdgcn_mfma_f32_16x16x32_bf16(
                        af[mf], bfr[nf], acc[mf][nf], 0, 0, 0);
            BARRIER();
        }
    } else {
        const bf16_t* wt1 = wsrc + (size_t)e1 * DIM * DIM;
        const bf16_t* wt2 = wsrc + (size_t)e2 * DIM * DIM;
        for (int ks = 0; ks < DIM / BK2; ks++) {
            int k0 = ks * BK2;
            #pragma unroll
            for (int i = 0; i < 2; i++)
                gload16(asrc[i] + k0, &As[0][(i * 256 + wv * 64) * 8]);
            #pragma unroll
            for (int i = 0; i < 2; i++) {
                int c = i * 256 + tid;
                int f = c >> 2, j = c & 3;
                const bf16_t* s1 = wt1 + (size_t)(n0 + f) * DIM + k0 + j * 8;
                const bf16_t* s2 = wt2 + (size_t)(n0 + f) * DIM + k0 + j * 8;
                bf16x8 u = *(const bf16x8*)s1, w2v = *(const bf16x8*)s2, o;
                #pragma unroll
                for (int t = 0; t < 8; t++) o[t] = (bf16_t)((float)u[t] + (float)w2v[t]);
                *(bf16x8*)((char*)Bs[0] + swz32(f, j * 8)) = o;
            }
            WAITCNT_LGKM0();
            WAITCNT_VM0();
            BARRIER();
            const char* Ab = (const char*)As[0];
            const char* Bb = (const char*)Bs[0];
            bf16x8 af[4], bfr[4];
            #pragma unroll
            for (int mf = 0; mf < 4; mf++)
                af[mf] = *(const bf16x8*)(Ab + swz32(wm * 64 + mf * 16 + lr, lk));
            #pragma unroll
            for (int nf = 0; nf < 4; nf++)
                bfr[nf] = *(const bf16x8*)(Bb + swz32(wn * 64 + nf * 16 + lr, lk));
            #pragma unroll
            for (int mf = 0; mf < 4; mf++)
                #pragma unroll
                for (int nf = 0; nf < 4; nf++)
                    acc[mf][nf] = __builtin_amdgcn_mfma_f32_16x16x32_bf16(
                        af[mf], bfr[nf], acc[mf][nf], 0, 0, 0);
            BARRIER();
        }
    }

    #pragma unroll
    for (int mf = 0; mf < 4; mf++) {
        #pragma unroll
        for (int reg = 0; reg < 4; reg++) {
            int rl = wm * 64 + mf * 16 + (lane >> 4) * 4 + reg;
            if (rl < valid) {
                size_t trow = (size_t)toks[rl] * DIM;
                #pragma unroll
                for (int nf = 0; nf < 4; nf++)
                    out[trow + n0 + wn * 64 + nf * 16 + lr] = acc[mf][nf][reg];
            }
        }
    }
}

// ------------------------------------------------------------------
extern "C" void kernel_launch(void* const* d_in, const int* in_sizes, int n_in,
                              void* d_out, int out_size, void* d_ws, size_t ws_size,
                              hipStream_t stream) {
    const float* x  = (const float*)d_in[0];
    const float* gw = (const float*)d_in[1];
    const float* gb = (const float*)d_in[2];
    const float* ew = (const float*)d_in[3];
    float* out = (float*)d_out;
    char* ws = (char*)d_ws;
    int*    cnt  = (int*)(ws + WS_CNT);
    int*    list = (int*)(ws + WS_LIST);
    bf16_t* xbf  = (bf16_t*)(ws + WS_XBF);
    bf16_t* w2   = (bf16_t*)(ws + WS_W2);
    bool psum = (ws_size >= WS_NEED_PSUM);

    zero_cnt<<<dim3(1), 256, 0, stream>>>((int4*)cnt);
    if (psum) {
        fused_pre<1><<<dim3(NR_ROUTE + 512), 256, 0, stream>>>(x, gw, gb, ew,
                                                               xbf, w2, cnt, list);
        moe_gemm<1><<<dim3(1024), 256, 0, stream>>>(xbf, w2, cnt, list, out);
    } else {
        fused_pre<0><<<dim3(NR_ROUTE + 8 * 256), 256, 0, stream>>>(x, gw, gb, ew,
                                                                   xbf, w2, cnt, list);
        moe_gemm<0><<<dim3(1024), 256, 0, stream>>>(xbf, w2, cnt, list, out);
    }
}